// Round 11
// baseline (1007.453 us; speedup 1.0000x reference)
//
#include <hip/hip_runtime.h>

typedef __attribute__((ext_vector_type(4))) float f32x4;
typedef __attribute__((ext_vector_type(8))) short bf16x8;
typedef unsigned int uint;
typedef unsigned short ushort;

#define mfma32 __builtin_amdgcn_mfma_f32_16x16x32_bf16

// ---------- helpers ----------

__device__ __forceinline__ ushort f2bf(float f) {
  union { float f; uint u; } v; v.f = f;
  uint u = v.u;
  uint r = (u + 0x7FFFu + ((u >> 16) & 1u)) >> 16;  // RNE
  return (ushort)r;
}
__device__ __forceinline__ float bf2f(ushort u) {
  union { uint u; float f; } v; v.u = ((uint)u) << 16;
  return v.f;
}

// packed f32x2 -> bf16x2 (RNE), 1 instruction
__device__ __forceinline__ uint cvt_pk_bf16(float lo, float hi) {
  uint r;
  asm("v_cvt_pk_bf16_f32 %0, %1, %2" : "=v"(r) : "v"(lo), "v"(hi));
  return r;
}

// exp2 (v_exp_f32 IS base-2 exp)
__device__ __forceinline__ float fexp2(float x) {
  float r;
  asm("v_exp_f32 %0, %1" : "=v"(r) : "v"(x));
  return r;
}

__device__ __forceinline__ void gload_lds16(const void* g, void* l) {
  __builtin_amdgcn_global_load_lds(
      (const __attribute__((address_space(1))) void*)g,
      (__attribute__((address_space(3))) void*)l, 16, 0, 0);
}

// ---------- pre-pass kernels ----------

// two f32->bf16 conversions in one dispatch (blockIdx selects source)
__global__ __launch_bounds__(256)
void conv_bf16_2(const float* __restrict__ a, const float* __restrict__ b,
                 ushort* __restrict__ oa, ushort* __restrict__ ob, long n) {
  const bool second = blockIdx.x >= 8192;
  const float* in = second ? b : a;
  ushort* out = second ? ob : oa;
  long i = ((long)(blockIdx.x & 8191) * 256 + threadIdx.x) * 8;
  if (i >= n) return;
  float4 x = *(const float4*)(in + i);
  float4 y = *(const float4*)(in + i + 4);
  union { uint u[4]; uint4 v; } o;
  o.u[0] = cvt_pk_bf16(x.x, x.y);
  o.u[1] = cvt_pk_bf16(x.z, x.w);
  o.u[2] = cvt_pk_bf16(y.x, y.y);
  o.u[3] = cvt_pk_bf16(y.z, y.w);
  *(uint4*)(out + i) = o.v;
}

// ---- vectorized 64x64 transpose -> bf16 (G13: 16B loads, 8B stores) ----

__global__ __launch_bounds__(256)
void transpose64f(const float* p0, const float* p1, const float* p2, const float* p3,
                  ushort* q0, ushort* q1, ushort* q2, ushort* q3, int R, int C) {
  __shared__ float tile[64][68];
  const int z = blockIdx.z;
  const float* in = z == 0 ? p0 : z == 1 ? p1 : z == 2 ? p2 : p3;
  ushort* out = z == 0 ? q0 : z == 1 ? q1 : z == 2 ? q2 : q3;
  const int r0 = blockIdx.y * 64, c0 = blockIdx.x * 64;
  const int tid = threadIdx.x;
#pragma unroll
  for (int j = 0; j < 4; ++j) {
    int flat = j * 256 + tid;
    int row = flat >> 4, c4 = (flat & 15) * 4;
    float4 v = *(const float4*)(in + (size_t)(r0 + row) * C + c0 + c4);
    *(float4*)&tile[row][c4] = v;
  }
  __syncthreads();
#pragma unroll
  for (int j = 0; j < 4; ++j) {
    int flat = j * 256 + tid;
    int oc = flat >> 4, rq = (flat & 15) * 4;
    uint2 w;
    w.x = cvt_pk_bf16(tile[rq + 0][oc], tile[rq + 1][oc]);
    w.y = cvt_pk_bf16(tile[rq + 2][oc], tile[rq + 3][oc]);
    *(uint2*)(out + (size_t)(c0 + oc) * R + r0 + rq) = w;
  }
}

__global__ __launch_bounds__(256)
void transpose64h(const ushort* p0, const ushort* p1, const ushort* p2, const ushort* p3,
                  ushort* q0, ushort* q1, ushort* q2, ushort* q3, int R, int C) {
  __shared__ float tile[64][68];
  const int z = blockIdx.z;
  const ushort* in = z == 0 ? p0 : z == 1 ? p1 : z == 2 ? p2 : p3;
  ushort* out = z == 0 ? q0 : z == 1 ? q1 : z == 2 ? q2 : q3;
  const int r0 = blockIdx.y * 64, c0 = blockIdx.x * 64;
  const int tid = threadIdx.x;
#pragma unroll
  for (int j = 0; j < 2; ++j) {
    int flat = j * 256 + tid;
    int row = flat >> 3, c8 = (flat & 7) * 8;
    uint4 v = *(const uint4*)(in + (size_t)(r0 + row) * C + c0 + c8);
    float4 f0, f1;
    f0.x = bf2f((ushort)(v.x & 0xffff)); f0.y = bf2f((ushort)(v.x >> 16));
    f0.z = bf2f((ushort)(v.y & 0xffff)); f0.w = bf2f((ushort)(v.y >> 16));
    f1.x = bf2f((ushort)(v.z & 0xffff)); f1.y = bf2f((ushort)(v.z >> 16));
    f1.z = bf2f((ushort)(v.w & 0xffff)); f1.w = bf2f((ushort)(v.w >> 16));
    *(float4*)&tile[row][c8] = f0;
    *(float4*)&tile[row][c8 + 4] = f1;
  }
  __syncthreads();
#pragma unroll
  for (int j = 0; j < 4; ++j) {
    int flat = j * 256 + tid;
    int oc = flat >> 4, rq = (flat & 15) * 4;
    uint2 w;
    w.x = cvt_pk_bf16(tile[rq + 0][oc], tile[rq + 1][oc]);
    w.y = cvt_pk_bf16(tile[rq + 2][oc], tile[rq + 3][oc]);
    *(uint2*)(out + (size_t)(c0 + oc) * R + r0 + rq) = w;
  }
}

__global__ __launch_bounds__(256)
void pack_mask(const int* __restrict__ in, uint* __restrict__ out) {
  long t = (long)blockIdx.x * 256 + threadIdx.x;
  const int4* p = (const int4*)(in + t * 32);
  uint w = 0;
#pragma unroll
  for (int i = 0; i < 8; ++i) {
    int4 v = p[i];
    w |= (v.x > 0 ? 1u : 0u) << (i * 4 + 0);
    w |= (v.y > 0 ? 1u : 0u) << (i * 4 + 1);
    w |= (v.z > 0 ? 1u : 0u) << (i * 4 + 2);
    w |= (v.w > 0 ? 1u : 0u) << (i * 4 + 3);
  }
  out[t] = w;
}

// ---------- GEMM: 256x256 tile, counted-vmcnt pipeline (unchanged r5) -------

template<int OUT_BF16>
__global__ __launch_bounds__(512, 2)
void gemm256(const ushort* __restrict__ A, const ushort* __restrict__ Bt,
             void* __restrict__ C, int M, int N, int K, float scale) {
  __shared__ ushort lA[2][256 * 64];
  __shared__ ushort lB[2][256 * 64];
  const int tid = threadIdx.x;
  const int wid = tid >> 6, lane = tid & 63;
  const int lg = lane >> 4, li = lane & 15;
  const int wm = wid >> 2, wn = wid & 3;
  const int m0 = blockIdx.y * 256, n0 = blockIdx.x * 256;

  int offA[4], offB[4];
#pragma unroll
  for (int i = 0; i < 4; ++i) {
    int off = i * 8192 + tid * 16;
    int row = off >> 7;
    int col = (off & 127) ^ ((row & 7) << 4);
    offA[i] = (m0 + row) * (K * 2) + col;
    offB[i] = (n0 + row) * (K * 2) + col;
  }
  const char* Ab = (const char*)A;
  const char* Bb = (const char*)Bt;

#define STAGE256(bufi, ktb)                                                   \
  do {                                                                        \
    _Pragma("unroll") for (int i = 0; i < 4; ++i)                             \
      gload_lds16(Ab + (size_t)(offA[i] + (ktb)),                             \
                  (char*)lA[bufi] + i * 8192 + wid * 1024);                   \
    _Pragma("unroll") for (int i = 0; i < 4; ++i)                             \
      gload_lds16(Bb + (size_t)(offB[i] + (ktb)),                             \
                  (char*)lB[bufi] + i * 8192 + wid * 1024);                   \
  } while (0)

  f32x4 acc[8][4] = {};
  const int NT = K >> 6;

  STAGE256(0, 0);

  for (int t = 0; t < NT; ++t) {
    const int cur = t & 1;
    if (t > 0) __builtin_amdgcn_s_barrier();
    if (t + 1 < NT) {
      STAGE256(cur ^ 1, (t + 1) * 128);
      asm volatile("s_waitcnt vmcnt(8)" ::: "memory");
    } else {
      asm volatile("s_waitcnt vmcnt(0)" ::: "memory");
    }
    __builtin_amdgcn_s_barrier();
    __builtin_amdgcn_sched_barrier(0);

    const char* la = (const char*)lA[cur];
    const char* lb = (const char*)lB[cur];
    bf16x8 afr[4][2];
#pragma unroll
    for (int q = 0; q < 4; ++q) {
      const int mh = q >> 1;
      const int nh = (q == 1 || q == 2) ? 1 : 0;
      if ((q & 1) == 0) {
#pragma unroll
        for (int mi = 0; mi < 4; ++mi)
#pragma unroll
          for (int ks = 0; ks < 2; ++ks) {
            const int row = wm * 128 + (mh * 4 + mi) * 16 + li;
            afr[mi][ks] = *(const bf16x8*)(
                la + row * 128 + ((ks * 64 + lg * 16) ^ ((li & 7) << 4)));
          }
      }
      bf16x8 bfr[2][2];
#pragma unroll
      for (int ni = 0; ni < 2; ++ni)
#pragma unroll
        for (int ks = 0; ks < 2; ++ks) {
          const int row = wn * 64 + (nh * 2 + ni) * 16 + li;
          bfr[ni][ks] = *(const bf16x8*)(
              lb + row * 128 + ((ks * 64 + lg * 16) ^ ((li & 7) << 4)));
        }
      __builtin_amdgcn_s_setprio(1);
#pragma unroll
      for (int ks = 0; ks < 2; ++ks)
#pragma unroll
        for (int mi = 0; mi < 4; ++mi)
#pragma unroll
          for (int ni = 0; ni < 2; ++ni)
            acc[mh * 4 + mi][nh * 2 + ni] = mfma32(
                afr[mi][ks], bfr[ni][ks], acc[mh * 4 + mi][nh * 2 + ni], 0, 0, 0);
      __builtin_amdgcn_s_setprio(0);
    }
  }
#undef STAGE256

  const int r0 = m0 + wm * 128 + lg * 4;
  const int c0 = n0 + wn * 64 + li;
#pragma unroll
  for (int mi = 0; mi < 8; ++mi)
#pragma unroll
    for (int ni = 0; ni < 4; ++ni)
#pragma unroll
      for (int r = 0; r < 4; ++r) {
        size_t idx = (size_t)(r0 + mi * 16 + r) * N + (c0 + ni * 16);
        float v = acc[mi][ni][r] * scale;
        if (OUT_BF16) ((ushort*)C)[idx] = f2bf(v);
        else          ((float*)C)[idx]  = v;
      }
}

// ---------- flash attention v7.1 ----------
// v7 with the V^T element-addressing fix: av(f,kc) = V^T row f*16+li,
// element cols it*64 + kc*32 + lg*8 (previous rev doubled kc and lg offsets
// by carrying BYTE offsets into element arithmetic). LDS 48 KB, 3 blocks/CU.

__global__ __launch_bounds__(256, 3)
void flash_attn7(const ushort* __restrict__ Q, const ushort* __restrict__ K,
                 const ushort* __restrict__ VT, const uint* __restrict__ maskp,
                 ushort* __restrict__ X) {
  __shared__ ushort lK[2][64 * 128];    // [kv][hd], 256-B rows, swz (row&15)<<4
  __shared__ ushort lP[4][2][16 * 64];  // per-wave, per-group P^T [q][k]

  const int tid = threadIdx.x;
  const int wid = tid >> 6;
  const int lane = tid & 63;
  const int lg = lane >> 4, li = lane & 15;

  // XCD-clustered: 1024 blocks; 8 bh per XCD, 16 q-tiles each
  const int flat = blockIdx.x;
  const int xcd = flat & 7;
  const int j = flat >> 3;
  const int bh = xcd * 8 + (j >> 4);
  const int qt = j & 15;
  const int b = bh >> 4, h = bh & 15;
  const int q0 = qt * 128;
  const int qbase = q0 + wid * 32;

  // Q as MFMA B-operand (16x16x32), 2 groups of 16 q
  bf16x8 bq[2][4];
#pragma unroll
  for (int g = 0; g < 2; ++g) {
    const ushort* qrow = Q + (size_t)(b * 2048 + qbase + g * 16 + li) * 2048 + h * 128;
#pragma unroll
    for (int kk = 0; kk < 4; ++kk)
      bq[g][kk] = *(const bf16x8*)(qrow + kk * 32 + lg * 8);
  }

  const uint* mqb[2] = {
      maskp + (size_t)(b * 2048 + qbase + li) * 64,
      maskp + (size_t)(b * 2048 + qbase + 16 + li) * 64};
  uint2 wcur[2] = {*(const uint2*)mqb[0], *(const uint2*)mqb[1]};

  f32x4 acc_o[2][8] = {};  // O^T[hd = f*16 + lg*4 + r][q = li]
  f32x4 acc_l[2] = {};     // every component = running row-sum l(q=li)
  float m[2] = {-3e38f, -3e38f};

  const short ob = (short)0x3F80;  // bf16 1.0
  const bf16x8 vone8 = {ob, ob, ob, ob, ob, ob, ob, ob};

  // K staging source pointers (pre-swizzled global col; advance per tile)
  const char* gk[4];
#pragma unroll
  for (int i = 0; i < 4; ++i) {
    int fl = i * 4096 + tid * 16;
    int rowK = fl >> 8;
    int colK = (fl & 255) ^ ((rowK & 15) << 4);
    gk[i] = (const char*)K + ((size_t)(b * 2048 + rowK) * 2048 + h * 128) * 2 + colK;
  }

  // V^T global base: av(f,kc) = row f*16+li, element cols it*64 + kc*32 + lg*8
  const ushort* vbase = VT + ((size_t)(b * 16 + h) * 128 + li) * 2048 + lg * 8;

#define FSTAGE(bufi)                                                          \
  do {                                                                        \
    _Pragma("unroll") for (int i = 0; i < 4; ++i)                             \
      gload_lds16(gk[i], (char*)lK[bufi] + i * 4096 + wid * 1024);            \
    _Pragma("unroll") for (int i = 0; i < 4; ++i) gk[i] += 262144;            \
  } while (0)

  FSTAGE(0);  // tile 0 (4 K-loads in flight)

  ushort* lp0 = lP[wid][0];
  ushort* lp1 = lP[wid][1];

#pragma unroll 2
  for (int it = 0; it < 32; ++it) {
    const int cur = it & 1;
    if (it > 0) __builtin_amdgcn_s_barrier();  // all waves done reading buf cur^1
    uint2 wn[2];
    if (it < 31) {
      FSTAGE(cur ^ 1);  // tile it+1: stays in flight across the barriers
      wn[0] = *(const uint2*)(mqb[0] + (it + 1) * 2);
      wn[1] = *(const uint2*)(mqb[1] + (it + 1) * 2);
      // retire tile it's 4 K-stages only (leave 4 K + 2 mask in flight)
      asm volatile("s_waitcnt vmcnt(6)" ::: "memory");
    } else {
      asm volatile("s_waitcnt vmcnt(0)" ::: "memory");
    }
    __builtin_amdgcn_s_barrier();              // tile it visible to all waves
    __builtin_amdgcn_sched_barrier(0);

    const char* lk = (const char*)lK[cur];
    const ushort* vit = vbase + it * 64;       // this tile's V^T columns

    // QK^T swapped (16x16x32): accs[g][n] = S[k=n*16+lg*4+r][q=li]
    f32x4 accs[2][4] = {};
    __builtin_amdgcn_s_setprio(1);
#pragma unroll
    for (int kk = 0; kk < 4; ++kk)
#pragma unroll
      for (int n = 0; n < 4; ++n) {
        bf16x8 ak = *(const bf16x8*)(lk + (n * 16 + li) * 256 +
                                     ((kk * 64 + lg * 16) ^ (li << 4)));
        accs[0][n] = mfma32(ak, bq[0][kk], accs[0][n], 0, 0, 0);
        accs[1][n] = mfma32(ak, bq[1][kk], accs[1][n], 0, 0, 0);
      }
    __builtin_amdgcn_s_setprio(0);

    // softmax per group (exp2 domain); P -> per-wave LDS via cvt_pk
#pragma unroll
    for (int g = 0; g < 2; ++g) {
      float sv[16];
#pragma unroll
      for (int n = 0; n < 4; ++n) {
        uint w = (n < 2) ? wcur[g].x : wcur[g].y;
#pragma unroll
        for (int r = 0; r < 4; ++r) {
          int bit = (n & 1) * 16 + lg * 4 + r;
          sv[n * 4 + r] = ((w >> bit) & 1u) ? accs[g][n][r] : -1e10f;
        }
      }
      // max3-fusable tree (T17)
      float t0 = fmaxf(fmaxf(sv[0], sv[1]), sv[2]);
      float t1 = fmaxf(fmaxf(sv[3], sv[4]), sv[5]);
      float t2 = fmaxf(fmaxf(sv[6], sv[7]), sv[8]);
      float t3 = fmaxf(fmaxf(sv[9], sv[10]), sv[11]);
      float t4 = fmaxf(fmaxf(sv[12], sv[13]), sv[14]);
      float pmax = fmaxf(fmaxf(fmaxf(t0, t1), t2),
                         fmaxf(fmaxf(t3, t4), sv[15]));
      pmax = fmaxf(pmax, __shfl_xor(pmax, 16, 64));
      pmax = fmaxf(pmax, __shfl_xor(pmax, 32, 64));

      // defer-max: 11.5 ~= 8 * log2(e)
      if (!__all(pmax - m[g] <= 11.5f)) {
        float mnew = fmaxf(m[g], pmax);
        float alpha = fexp2(m[g] - mnew);
#pragma unroll
        for (int r = 0; r < 4; ++r) acc_l[g][r] *= alpha;
#pragma unroll
        for (int f = 0; f < 8; ++f)
#pragma unroll
          for (int r = 0; r < 4; ++r) acc_o[g][f][r] *= alpha;
        m[g] = mnew;
      }

      uint pk[8];
#pragma unroll
      for (int i = 0; i < 8; ++i) {
        float p0 = fexp2(sv[2 * i] - m[g]);      // bounded by 2^11.5
        float p1 = fexp2(sv[2 * i + 1] - m[g]);
        pk[i] = cvt_pk_bf16(p0, p1);
      }

      ushort* lpg = g ? lp1 : lp0;
#pragma unroll
      for (int n = 0; n < 4; ++n) {
        uint2 pw; pw.x = pk[2 * n]; pw.y = pk[2 * n + 1];
        *(uint2*)((char*)lpg + li * 128 + ((n * 32 + lg * 8) ^ ((li & 7) << 4))) = pw;
      }
    }
    // in-order per-wave DS pipe: ds_write -> ds_read RAW safe without barrier

    // PV fused over both groups (16x16x32): av from GLOBAL V^T (L2/L3-resident)
    // l accumulated via ones-MFMA on the same bp fragments.
    __builtin_amdgcn_s_setprio(1);
#pragma unroll
    for (int kc = 0; kc < 2; ++kc) {
      bf16x8 bp0 = *(const bf16x8*)((const char*)lp0 + li * 128 +
                                    ((kc * 64 + lg * 16) ^ ((li & 7) << 4)));
      bf16x8 bp1 = *(const bf16x8*)((const char*)lp1 + li * 128 +
                                    ((kc * 64 + lg * 16) ^ ((li & 7) << 4)));
      acc_l[0] = mfma32(vone8, bp0, acc_l[0], 0, 0, 0);
      acc_l[1] = mfma32(vone8, bp1, acc_l[1], 0, 0, 0);
#pragma unroll
      for (int f = 0; f < 8; ++f) {
        bf16x8 av = *(const bf16x8*)(vit + f * 32768 + kc * 32);
        acc_o[0][f] = mfma32(av, bp0, acc_o[0][f], 0, 0, 0);
        acc_o[1][f] = mfma32(av, bp1, acc_o[1][f], 0, 0, 0);
      }
    }
    __builtin_amdgcn_s_setprio(0);

    if (it < 31) { wcur[0] = wn[0]; wcur[1] = wn[1]; }
  }
#undef FSTAGE

  // epilogue: O[q][hd] = acc_o / l  (acc_l rows all equal l(q=li))
#pragma unroll
  for (int g = 0; g < 2; ++g) {
    const float inv_l = 1.0f / acc_l[g][0];
    ushort* xrow = X + (size_t)(b * 2048 + qbase + g * 16 + li) * 2048 + h * 128;
#pragma unroll
    for (int f = 0; f < 8; ++f) {
      union { ushort u[4]; uint2 v; } o;
#pragma unroll
      for (int r = 0; r < 4; ++r) o.u[r] = f2bf(acc_o[g][f][r] * inv_l);
      *(uint2*)(xrow + f * 16 + lg * 4) = o.v;
    }
  }
}

// ---------- launch ----------

extern "C" void kernel_launch(void* const* d_in, const int* in_sizes, int n_in,
                              void* d_out, int out_size, void* d_ws, size_t ws_size,
                              hipStream_t stream) {
  const float* inputs_q  = (const float*)d_in[0];
  const float* inputs_kv = (const float*)d_in[1];
  const int*   mask      = (const int*)d_in[2];
  const float* Wq        = (const float*)d_in[3];
  const float* Wk        = (const float*)d_in[4];
  const float* Wv        = (const float*)d_in[5];
  const float* Wo        = (const float*)d_in[6];
  float* out = (float*)d_out;
  char* ws = (char*)d_ws;

  uint*   maskp = (uint*)(ws + 0);                 //   2,097,152
  ushort* xq    = (ushort*)(ws + 2097152);         //  33,554,432 (reused as VT)
  ushort* xkv   = (ushort*)(ws + 35651584);        //  33,554,432 (reused as X)
  ushort* WqT   = (ushort*)(ws + 69206016);        //   8,388,608
  ushort* WkT   = (ushort*)(ws + 77594624);
  ushort* WvT   = (ushort*)(ws + 85983232);
  ushort* WoT   = (ushort*)(ws + 94371840);
  ushort* Qb    = (ushort*)(ws + 102760448);       //  33,554,432
  ushort* Kb    = (ushort*)(ws + 136314880);
  ushort* Vb    = (ushort*)(ws + 169869312);
  ushort* VTb   = xq;   // V^T, written after xq dead
  ushort* Xb    = xkv;  // attention output, written after xkv dead

  const long NE = 8192L * 2048;
  conv_bf16_2<<<16384, 256, 0, stream>>>(inputs_q, inputs_kv, xq, xkv, NE);

  transpose64f<<<dim3(32, 32, 4), 256, 0, stream>>>(
      Wq, Wk, Wv, Wo, WqT, WkT, WvT, WoT, 2048, 2048);

  pack_mask<<<2048, 256, 0, stream>>>(mask, maskp);

  // 1/sqrt(128) * log2(e): softmax runs in exp2 domain
  const float qscale = 0.12751744504593677f;
  gemm256<1><<<dim3(8, 32), 512, 0, stream>>>(xq,  WqT, Qb, 8192, 2048, 2048, qscale);
  gemm256<1><<<dim3(8, 32), 512, 0, stream>>>(xkv, WkT, Kb, 8192, 2048, 2048, 1.0f);
  gemm256<1><<<dim3(8, 32), 512, 0, stream>>>(xkv, WvT, Vb, 8192, 2048, 2048, 1.0f);

  const long BS = 2048L * 2048;
  transpose64h<<<dim3(32, 32, 4), 256, 0, stream>>>(
      Vb, Vb + BS, Vb + 2 * BS, Vb + 3 * BS,
      VTb, VTb + BS, VTb + 2 * BS, VTb + 3 * BS, 2048, 2048);

  flash_attn7<<<1024, 256, 0, stream>>>(Qb, Kb, VTb, maskp, Xb);

  gemm256<0><<<dim3(8, 32), 512, 0, stream>>>(Xb, WoT, out, 8192, 2048, 2048, 1.0f);
}

// Round 12
// 580.215 us; speedup vs baseline: 1.7363x; 1.7363x over previous
//
#include <hip/hip_runtime.h>

typedef __attribute__((ext_vector_type(4))) float f32x4;
typedef __attribute__((ext_vector_type(8))) short bf16x8;
typedef unsigned int uint;
typedef unsigned short ushort;

#define mfma32 __builtin_amdgcn_mfma_f32_16x16x32_bf16

// ---------- helpers ----------

__device__ __forceinline__ ushort f2bf(float f) {
  union { float f; uint u; } v; v.f = f;
  uint u = v.u;
  uint r = (u + 0x7FFFu + ((u >> 16) & 1u)) >> 16;  // RNE
  return (ushort)r;
}
__device__ __forceinline__ float bf2f(ushort u) {
  union { uint u; float f; } v; v.u = ((uint)u) << 16;
  return v.f;
}

// packed f32x2 -> bf16x2 (RNE), 1 instruction
__device__ __forceinline__ uint cvt_pk_bf16(float lo, float hi) {
  uint r;
  asm("v_cvt_pk_bf16_f32 %0, %1, %2" : "=v"(r) : "v"(lo), "v"(hi));
  return r;
}

// exp2 (v_exp_f32 IS base-2 exp)
__device__ __forceinline__ float fexp2(float x) {
  float r;
  asm("v_exp_f32 %0, %1" : "=v"(r) : "v"(x));
  return r;
}

__device__ __forceinline__ void gload_lds16(const void* g, void* l) {
  __builtin_amdgcn_global_load_lds(
      (const __attribute__((address_space(1))) void*)g,
      (__attribute__((address_space(3))) void*)l, 16, 0, 0);
}

// ---------- pre-pass kernels ----------

// two f32->bf16 conversions in one dispatch (blockIdx selects source)
__global__ __launch_bounds__(256)
void conv_bf16_2(const float* __restrict__ a, const float* __restrict__ b,
                 ushort* __restrict__ oa, ushort* __restrict__ ob, long n) {
  const bool second = blockIdx.x >= 8192;
  const float* in = second ? b : a;
  ushort* out = second ? ob : oa;
  long i = ((long)(blockIdx.x & 8191) * 256 + threadIdx.x) * 8;
  if (i >= n) return;
  float4 x = *(const float4*)(in + i);
  float4 y = *(const float4*)(in + i + 4);
  union { uint u[4]; uint4 v; } o;
  o.u[0] = cvt_pk_bf16(x.x, x.y);
  o.u[1] = cvt_pk_bf16(x.z, x.w);
  o.u[2] = cvt_pk_bf16(y.x, y.y);
  o.u[3] = cvt_pk_bf16(y.z, y.w);
  *(uint4*)(out + i) = o.v;
}

// ---- vectorized 64x64 transpose -> bf16 (G13: 16B loads, 8B stores) ----

__global__ __launch_bounds__(256)
void transpose64f(const float* p0, const float* p1, const float* p2, const float* p3,
                  ushort* q0, ushort* q1, ushort* q2, ushort* q3, int R, int C) {
  __shared__ float tile[64][68];
  const int z = blockIdx.z;
  const float* in = z == 0 ? p0 : z == 1 ? p1 : z == 2 ? p2 : p3;
  ushort* out = z == 0 ? q0 : z == 1 ? q1 : z == 2 ? q2 : q3;
  const int r0 = blockIdx.y * 64, c0 = blockIdx.x * 64;
  const int tid = threadIdx.x;
#pragma unroll
  for (int j = 0; j < 4; ++j) {
    int flat = j * 256 + tid;
    int row = flat >> 4, c4 = (flat & 15) * 4;
    float4 v = *(const float4*)(in + (size_t)(r0 + row) * C + c0 + c4);
    *(float4*)&tile[row][c4] = v;
  }
  __syncthreads();
#pragma unroll
  for (int j = 0; j < 4; ++j) {
    int flat = j * 256 + tid;
    int oc = flat >> 4, rq = (flat & 15) * 4;
    uint2 w;
    w.x = cvt_pk_bf16(tile[rq + 0][oc], tile[rq + 1][oc]);
    w.y = cvt_pk_bf16(tile[rq + 2][oc], tile[rq + 3][oc]);
    *(uint2*)(out + (size_t)(c0 + oc) * R + r0 + rq) = w;
  }
}

__global__ __launch_bounds__(256)
void transpose64h(const ushort* p0, const ushort* p1, const ushort* p2, const ushort* p3,
                  ushort* q0, ushort* q1, ushort* q2, ushort* q3, int R, int C) {
  __shared__ float tile[64][68];
  const int z = blockIdx.z;
  const ushort* in = z == 0 ? p0 : z == 1 ? p1 : z == 2 ? p2 : p3;
  ushort* out = z == 0 ? q0 : z == 1 ? q1 : z == 2 ? q2 : q3;
  const int r0 = blockIdx.y * 64, c0 = blockIdx.x * 64;
  const int tid = threadIdx.x;
#pragma unroll
  for (int j = 0; j < 2; ++j) {
    int flat = j * 256 + tid;
    int row = flat >> 3, c8 = (flat & 7) * 8;
    uint4 v = *(const uint4*)(in + (size_t)(r0 + row) * C + c0 + c8);
    float4 f0, f1;
    f0.x = bf2f((ushort)(v.x & 0xffff)); f0.y = bf2f((ushort)(v.x >> 16));
    f0.z = bf2f((ushort)(v.y & 0xffff)); f0.w = bf2f((ushort)(v.y >> 16));
    f1.x = bf2f((ushort)(v.z & 0xffff)); f1.y = bf2f((ushort)(v.z >> 16));
    f1.z = bf2f((ushort)(v.w & 0xffff)); f1.w = bf2f((ushort)(v.w >> 16));
    *(float4*)&tile[row][c8] = f0;
    *(float4*)&tile[row][c8 + 4] = f1;
  }
  __syncthreads();
#pragma unroll
  for (int j = 0; j < 4; ++j) {
    int flat = j * 256 + tid;
    int oc = flat >> 4, rq = (flat & 15) * 4;
    uint2 w;
    w.x = cvt_pk_bf16(tile[rq + 0][oc], tile[rq + 1][oc]);
    w.y = cvt_pk_bf16(tile[rq + 2][oc], tile[rq + 3][oc]);
    *(uint2*)(out + (size_t)(c0 + oc) * R + r0 + rq) = w;
  }
}

__global__ __launch_bounds__(256)
void pack_mask(const int* __restrict__ in, uint* __restrict__ out) {
  long t = (long)blockIdx.x * 256 + threadIdx.x;
  const int4* p = (const int4*)(in + t * 32);
  uint w = 0;
#pragma unroll
  for (int i = 0; i < 8; ++i) {
    int4 v = p[i];
    w |= (v.x > 0 ? 1u : 0u) << (i * 4 + 0);
    w |= (v.y > 0 ? 1u : 0u) << (i * 4 + 1);
    w |= (v.z > 0 ? 1u : 0u) << (i * 4 + 2);
    w |= (v.w > 0 ? 1u : 0u) << (i * 4 + 3);
  }
  out[t] = w;
}

// ---------- GEMM: 256x256 tile, counted-vmcnt pipeline ----------

template<int OUT_BF16>
__global__ __launch_bounds__(512, 2)
void gemm256(const ushort* __restrict__ A, const ushort* __restrict__ Bt,
             void* __restrict__ C, int M, int N, int K, float scale) {
  __shared__ ushort lA[2][256 * 64];
  __shared__ ushort lB[2][256 * 64];
  const int tid = threadIdx.x;
  const int wid = tid >> 6, lane = tid & 63;
  const int lg = lane >> 4, li = lane & 15;
  const int wm = wid >> 2, wn = wid & 3;
  const int m0 = blockIdx.y * 256, n0 = blockIdx.x * 256;

  int offA[4], offB[4];
#pragma unroll
  for (int i = 0; i < 4; ++i) {
    int off = i * 8192 + tid * 16;
    int row = off >> 7;
    int col = (off & 127) ^ ((row & 7) << 4);
    offA[i] = (m0 + row) * (K * 2) + col;
    offB[i] = (n0 + row) * (K * 2) + col;
  }
  const char* Ab = (const char*)A;
  const char* Bb = (const char*)Bt;

#define STAGE256(bufi, ktb)                                                   \
  do {                                                                        \
    _Pragma("unroll") for (int i = 0; i < 4; ++i)                             \
      gload_lds16(Ab + (size_t)(offA[i] + (ktb)),                             \
                  (char*)lA[bufi] + i * 8192 + wid * 1024);                   \
    _Pragma("unroll") for (int i = 0; i < 4; ++i)                             \
      gload_lds16(Bb + (size_t)(offB[i] + (ktb)),                             \
                  (char*)lB[bufi] + i * 8192 + wid * 1024);                   \
  } while (0)

  f32x4 acc[8][4] = {};
  const int NT = K >> 6;

  STAGE256(0, 0);

  for (int t = 0; t < NT; ++t) {
    const int cur = t & 1;
    if (t > 0) __builtin_amdgcn_s_barrier();
    if (t + 1 < NT) {
      STAGE256(cur ^ 1, (t + 1) * 128);
      asm volatile("s_waitcnt vmcnt(8)" ::: "memory");
    } else {
      asm volatile("s_waitcnt vmcnt(0)" ::: "memory");
    }
    __builtin_amdgcn_s_barrier();
    __builtin_amdgcn_sched_barrier(0);

    const char* la = (const char*)lA[cur];
    const char* lb = (const char*)lB[cur];
    bf16x8 afr[4][2];
#pragma unroll
    for (int q = 0; q < 4; ++q) {
      const int mh = q >> 1;
      const int nh = (q == 1 || q == 2) ? 1 : 0;
      if ((q & 1) == 0) {
#pragma unroll
        for (int mi = 0; mi < 4; ++mi)
#pragma unroll
          for (int ks = 0; ks < 2; ++ks) {
            const int row = wm * 128 + (mh * 4 + mi) * 16 + li;
            afr[mi][ks] = *(const bf16x8*)(
                la + row * 128 + ((ks * 64 + lg * 16) ^ ((li & 7) << 4)));
          }
      }
      bf16x8 bfr[2][2];
#pragma unroll
      for (int ni = 0; ni < 2; ++ni)
#pragma unroll
        for (int ks = 0; ks < 2; ++ks) {
          const int row = wn * 64 + (nh * 2 + ni) * 16 + li;
          bfr[ni][ks] = *(const bf16x8*)(
              lb + row * 128 + ((ks * 64 + lg * 16) ^ ((li & 7) << 4)));
        }
      __builtin_amdgcn_s_setprio(1);
#pragma unroll
      for (int ks = 0; ks < 2; ++ks)
#pragma unroll
        for (int mi = 0; mi < 4; ++mi)
#pragma unroll
          for (int ni = 0; ni < 2; ++ni)
            acc[mh * 4 + mi][nh * 2 + ni] = mfma32(
                afr[mi][ks], bfr[ni][ks], acc[mh * 4 + mi][nh * 2 + ni], 0, 0, 0);
      __builtin_amdgcn_s_setprio(0);
    }
  }
#undef STAGE256

  const int r0 = m0 + wm * 128 + lg * 4;
  const int c0 = n0 + wn * 64 + li;
#pragma unroll
  for (int mi = 0; mi < 8; ++mi)
#pragma unroll
    for (int ni = 0; ni < 4; ++ni)
#pragma unroll
      for (int r = 0; r < 4; ++r) {
        size_t idx = (size_t)(r0 + mi * 16 + r) * N + (c0 + ni * 16);
        float v = acc[mi][ni][r] * scale;
        if (OUT_BF16) ((ushort*)C)[idx] = f2bf(v);
        else          ((float*)C)[idx]  = v;
      }
}

// ---------- flash attention v6.1 (round-9 verified: 199.5 us) ----------
// 16x16x32 MFMA everywhere, P via per-wave LDS, b128 V^T reads from LDS,
// counted-vmcnt 2-raw-barrier pipeline, exp2 softmax, l via ones-MFMA,
// setprio around MFMA clusters, max3 tree. LDS 80 KB, 2 blocks/CU.

__global__ __launch_bounds__(256, 2)
void flash_attn6(const ushort* __restrict__ Q, const ushort* __restrict__ K,
                 const ushort* __restrict__ VT, const uint* __restrict__ maskp,
                 ushort* __restrict__ X) {
  __shared__ ushort lK[2][64 * 128];    // [kv][hd], 256-B rows, swz (row&15)<<4
  __shared__ ushort lVT[2][128 * 64];   // [hd][kv], 128-B rows, swz (row&7)<<4
  __shared__ ushort lP[4][2][16 * 64];  // per-wave, per-group P^T [q][k]

  const int tid = threadIdx.x;
  const int wid = tid >> 6;
  const int lane = tid & 63;
  const int lg = lane >> 4, li = lane & 15;

  const int flat = blockIdx.x;
  const int xcd = flat & 7;
  const int j = flat >> 3;
  const int bh = xcd * 8 + (j >> 4);
  const int qt = j & 15;
  const int b = bh >> 4, h = bh & 15;
  const int q0 = qt * 128;
  const int qbase = q0 + wid * 32;

  bf16x8 bq[2][4];
#pragma unroll
  for (int g = 0; g < 2; ++g) {
    const ushort* qrow = Q + (size_t)(b * 2048 + qbase + g * 16 + li) * 2048 + h * 128;
#pragma unroll
    for (int kk = 0; kk < 4; ++kk)
      bq[g][kk] = *(const bf16x8*)(qrow + kk * 32 + lg * 8);
  }

  const uint* mqb[2] = {
      maskp + (size_t)(b * 2048 + qbase + li) * 64,
      maskp + (size_t)(b * 2048 + qbase + 16 + li) * 64};
  uint2 wcur[2] = {*(const uint2*)mqb[0], *(const uint2*)mqb[1]};

  f32x4 acc_o[2][8] = {};  // O^T[hd = f*16 + lg*4 + r][q = li]
  f32x4 acc_l[2] = {};     // every component = running row-sum l(q=li)
  float m[2] = {-3e38f, -3e38f};

  const short ob = (short)0x3F80;  // bf16 1.0
  const bf16x8 vone8 = {ob, ob, ob, ob, ob, ob, ob, ob};

  const char* gk[4];
  const char* gv[4];
#pragma unroll
  for (int i = 0; i < 4; ++i) {
    int fl = i * 4096 + tid * 16;
    int rowK = fl >> 8;
    int colK = (fl & 255) ^ ((rowK & 15) << 4);
    gk[i] = (const char*)K + ((size_t)(b * 2048 + rowK) * 2048 + h * 128) * 2 + colK;
    int rowV = fl >> 7;
    int colV = (fl & 127) ^ ((rowV & 7) << 4);
    gv[i] = (const char*)VT + ((size_t)((b * 16 + h) * 128 + rowV) * 2048) * 2 + colV;
  }

#define FSTAGE(bufi)                                                          \
  do {                                                                        \
    _Pragma("unroll") for (int i = 0; i < 4; ++i)                             \
      gload_lds16(gk[i], (char*)lK[bufi] + i * 4096 + wid * 1024);            \
    _Pragma("unroll") for (int i = 0; i < 4; ++i)                             \
      gload_lds16(gv[i], (char*)lVT[bufi] + i * 4096 + wid * 1024);           \
    _Pragma("unroll") for (int i = 0; i < 4; ++i) {                           \
      gk[i] += 262144; gv[i] += 128;                                          \
    }                                                                         \
  } while (0)

  FSTAGE(0);

  ushort* lp0 = lP[wid][0];
  ushort* lp1 = lP[wid][1];

#pragma unroll 2
  for (int it = 0; it < 32; ++it) {
    const int cur = it & 1;
    if (it > 0) __builtin_amdgcn_s_barrier();
    uint2 wn[2];
    if (it < 31) {
      FSTAGE(cur ^ 1);
      wn[0] = *(const uint2*)(mqb[0] + (it + 1) * 2);
      wn[1] = *(const uint2*)(mqb[1] + (it + 1) * 2);
      asm volatile("s_waitcnt vmcnt(10)" ::: "memory");
    } else {
      asm volatile("s_waitcnt vmcnt(0)" ::: "memory");
    }
    __builtin_amdgcn_s_barrier();
    __builtin_amdgcn_sched_barrier(0);

    const char* lk = (const char*)lK[cur];
    const char* lv = (const char*)lVT[cur];

    // QK^T swapped (16x16x32): accs[g][n] = S[k=n*16+lg*4+r][q=li]
    f32x4 accs[2][4] = {};
    __builtin_amdgcn_s_setprio(1);
#pragma unroll
    for (int kk = 0; kk < 4; ++kk)
#pragma unroll
      for (int n = 0; n < 4; ++n) {
        bf16x8 ak = *(const bf16x8*)(lk + (n * 16 + li) * 256 +
                                     ((kk * 64 + lg * 16) ^ (li << 4)));
        accs[0][n] = mfma32(ak, bq[0][kk], accs[0][n], 0, 0, 0);
        accs[1][n] = mfma32(ak, bq[1][kk], accs[1][n], 0, 0, 0);
      }
    __builtin_amdgcn_s_setprio(0);

    // softmax per group (exp2 domain); P -> per-wave LDS via cvt_pk
#pragma unroll
    for (int g = 0; g < 2; ++g) {
      float sv[16];
#pragma unroll
      for (int n = 0; n < 4; ++n) {
        uint w = (n < 2) ? wcur[g].x : wcur[g].y;
#pragma unroll
        for (int r = 0; r < 4; ++r) {
          int bit = (n & 1) * 16 + lg * 4 + r;
          sv[n * 4 + r] = ((w >> bit) & 1u) ? accs[g][n][r] : -1e10f;
        }
      }
      // max3-fusable tree (T17)
      float t0 = fmaxf(fmaxf(sv[0], sv[1]), sv[2]);
      float t1 = fmaxf(fmaxf(sv[3], sv[4]), sv[5]);
      float t2 = fmaxf(fmaxf(sv[6], sv[7]), sv[8]);
      float t3 = fmaxf(fmaxf(sv[9], sv[10]), sv[11]);
      float t4 = fmaxf(fmaxf(sv[12], sv[13]), sv[14]);
      float pmax = fmaxf(fmaxf(fmaxf(t0, t1), t2),
                         fmaxf(fmaxf(t3, t4), sv[15]));
      pmax = fmaxf(pmax, __shfl_xor(pmax, 16, 64));
      pmax = fmaxf(pmax, __shfl_xor(pmax, 32, 64));

      // defer-max: 11.5 ~= 8 * log2(e)
      if (!__all(pmax - m[g] <= 11.5f)) {
        float mnew = fmaxf(m[g], pmax);
        float alpha = fexp2(m[g] - mnew);
#pragma unroll
        for (int r = 0; r < 4; ++r) acc_l[g][r] *= alpha;
#pragma unroll
        for (int f = 0; f < 8; ++f)
#pragma unroll
          for (int r = 0; r < 4; ++r) acc_o[g][f][r] *= alpha;
        m[g] = mnew;
      }

      uint pk[8];
#pragma unroll
      for (int i = 0; i < 8; ++i) {
        float p0 = fexp2(sv[2 * i] - m[g]);      // bounded by 2^11.5
        float p1 = fexp2(sv[2 * i + 1] - m[g]);
        pk[i] = cvt_pk_bf16(p0, p1);
      }

      ushort* lpg = g ? lp1 : lp0;
#pragma unroll
      for (int n = 0; n < 4; ++n) {
        uint2 pw; pw.x = pk[2 * n]; pw.y = pk[2 * n + 1];
        *(uint2*)((char*)lpg + li * 128 + ((n * 32 + lg * 8) ^ ((li & 7) << 4))) = pw;
      }
    }
    // in-order per-wave DS pipe: ds_write -> ds_read RAW safe without barrier

    // PV fused over both groups (16x16x32): av read ONCE per (kc,f);
    // l accumulated via ones-MFMA on the same bp fragments.
    __builtin_amdgcn_s_setprio(1);
#pragma unroll
    for (int kc = 0; kc < 2; ++kc) {
      bf16x8 bp0 = *(const bf16x8*)((const char*)lp0 + li * 128 +
                                    ((kc * 64 + lg * 16) ^ ((li & 7) << 4)));
      bf16x8 bp1 = *(const bf16x8*)((const char*)lp1 + li * 128 +
                                    ((kc * 64 + lg * 16) ^ ((li & 7) << 4)));
      acc_l[0] = mfma32(vone8, bp0, acc_l[0], 0, 0, 0);
      acc_l[1] = mfma32(vone8, bp1, acc_l[1], 0, 0, 0);
#pragma unroll
      for (int f = 0; f < 8; ++f) {
        bf16x8 av = *(const bf16x8*)(lv + (f * 16 + li) * 128 +
                                     ((kc * 64 + lg * 16) ^ ((li & 7) << 4)));
        acc_o[0][f] = mfma32(av, bp0, acc_o[0][f], 0, 0, 0);
        acc_o[1][f] = mfma32(av, bp1, acc_o[1][f], 0, 0, 0);
      }
    }
    __builtin_amdgcn_s_setprio(0);

    if (it < 31) { wcur[0] = wn[0]; wcur[1] = wn[1]; }
  }
#undef FSTAGE

  // epilogue: O[q][hd] = acc_o / l  (acc_l rows all equal l(q=li))
#pragma unroll
  for (int g = 0; g < 2; ++g) {
    const float inv_l = 1.0f / acc_l[g][0];
    ushort* xrow = X + (size_t)(b * 2048 + qbase + g * 16 + li) * 2048 + h * 128;
#pragma unroll
    for (int f = 0; f < 8; ++f) {
      union { ushort u[4]; uint2 v; } o;
#pragma unroll
      for (int r = 0; r < 4; ++r) o.u[r] = f2bf(acc_o[g][f][r] * inv_l);
      *(uint2*)(xrow + f * 16 + lg * 4) = o.v;
    }
  }
}

// ---------- launch ----------

extern "C" void kernel_launch(void* const* d_in, const int* in_sizes, int n_in,
                              void* d_out, int out_size, void* d_ws, size_t ws_size,
                              hipStream_t stream) {
  const float* inputs_q  = (const float*)d_in[0];
  const float* inputs_kv = (const float*)d_in[1];
  const int*   mask      = (const int*)d_in[2];
  const float* Wq        = (const float*)d_in[3];
  const float* Wk        = (const float*)d_in[4];
  const float* Wv        = (const float*)d_in[5];
  const float* Wo        = (const float*)d_in[6];
  float* out = (float*)d_out;
  char* ws = (char*)d_ws;

  uint*   maskp = (uint*)(ws + 0);                 //   2,097,152
  ushort* xq    = (ushort*)(ws + 2097152);         //  33,554,432 (reused as VT)
  ushort* xkv   = (ushort*)(ws + 35651584);        //  33,554,432 (reused as X)
  ushort* WqT   = (ushort*)(ws + 69206016);        //   8,388,608
  ushort* WkT   = (ushort*)(ws + 77594624);
  ushort* WvT   = (ushort*)(ws + 85983232);
  ushort* WoT   = (ushort*)(ws + 94371840);
  ushort* Qb    = (ushort*)(ws + 102760448);       //  33,554,432
  ushort* Kb    = (ushort*)(ws + 136314880);
  ushort* Vb    = (ushort*)(ws + 169869312);
  ushort* VTb   = xq;   // V^T, written after xq dead
  ushort* Xb    = xkv;  // attention output, written after xkv dead

  const long NE = 8192L * 2048;
  conv_bf16_2<<<16384, 256, 0, stream>>>(inputs_q, inputs_kv, xq, xkv, NE);

  transpose64f<<<dim3(32, 32, 4), 256, 0, stream>>>(
      Wq, Wk, Wv, Wo, WqT, WkT, WvT, WoT, 2048, 2048);

  pack_mask<<<2048, 256, 0, stream>>>(mask, maskp);

  // 1/sqrt(128) * log2(e): softmax runs in exp2 domain
  const float qscale = 0.12751744504593677f;
  gemm256<1><<<dim3(8, 32), 512, 0, stream>>>(xq,  WqT, Qb, 8192, 2048, 2048, qscale);
  gemm256<1><<<dim3(8, 32), 512, 0, stream>>>(xkv, WkT, Kb, 8192, 2048, 2048, 1.0f);
  gemm256<1><<<dim3(8, 32), 512, 0, stream>>>(xkv, WvT, Vb, 8192, 2048, 2048, 1.0f);

  const long BS = 2048L * 2048;
  transpose64h<<<dim3(32, 32, 4), 256, 0, stream>>>(
      Vb, Vb + BS, Vb + 2 * BS, Vb + 3 * BS,
      VTb, VTb + BS, VTb + 2 * BS, VTb + 3 * BS, 2048, 2048);

  flash_attn6<<<1024, 256, 0, stream>>>(Qb, Kb, VTb, maskp, Xb);

  gemm256<0><<<dim3(8, 32), 512, 0, stream>>>(Xb, WoT, out, 8192, 2048, 2048, 1.0f);
}

// Round 13
// 569.325 us; speedup vs baseline: 1.7696x; 1.0191x over previous
//
#include <hip/hip_runtime.h>

typedef __attribute__((ext_vector_type(4))) float f32x4;
typedef __attribute__((ext_vector_type(8))) short bf16x8;
typedef unsigned int uint;
typedef unsigned short ushort;

#define mfma32 __builtin_amdgcn_mfma_f32_16x16x32_bf16

// ---------- helpers ----------

__device__ __forceinline__ ushort f2bf(float f) {
  union { float f; uint u; } v; v.f = f;
  uint u = v.u;
  uint r = (u + 0x7FFFu + ((u >> 16) & 1u)) >> 16;  // RNE
  return (ushort)r;
}
__device__ __forceinline__ float bf2f(ushort u) {
  union { uint u; float f; } v; v.u = ((uint)u) << 16;
  return v.f;
}

// packed f32x2 -> bf16x2 (RNE), 1 instruction
__device__ __forceinline__ uint cvt_pk_bf16(float lo, float hi) {
  uint r;
  asm("v_cvt_pk_bf16_f32 %0, %1, %2" : "=v"(r) : "v"(lo), "v"(hi));
  return r;
}

// exp2 (v_exp_f32 IS base-2 exp)
__device__ __forceinline__ float fexp2(float x) {
  float r;
  asm("v_exp_f32 %0, %1" : "=v"(r) : "v"(x));
  return r;
}

__device__ __forceinline__ void gload_lds16(const void* g, void* l) {
  __builtin_amdgcn_global_load_lds(
      (const __attribute__((address_space(1))) void*)g,
      (__attribute__((address_space(3))) void*)l, 16, 0, 0);
}

// ---------- pre-pass kernels ----------

// two f32->bf16 conversions in one dispatch (blockIdx selects source)
__global__ __launch_bounds__(256)
void conv_bf16_2(const float* __restrict__ a, const float* __restrict__ b,
                 ushort* __restrict__ oa, ushort* __restrict__ ob, long n) {
  const bool second = blockIdx.x >= 8192;
  const float* in = second ? b : a;
  ushort* out = second ? ob : oa;
  long i = ((long)(blockIdx.x & 8191) * 256 + threadIdx.x) * 8;
  if (i >= n) return;
  float4 x = *(const float4*)(in + i);
  float4 y = *(const float4*)(in + i + 4);
  union { uint u[4]; uint4 v; } o;
  o.u[0] = cvt_pk_bf16(x.x, x.y);
  o.u[1] = cvt_pk_bf16(x.z, x.w);
  o.u[2] = cvt_pk_bf16(y.x, y.y);
  o.u[3] = cvt_pk_bf16(y.z, y.w);
  *(uint4*)(out + i) = o.v;
}

// ---- vectorized 64x64 transpose -> bf16 (G13: 16B loads, 8B stores) ----

__global__ __launch_bounds__(256)
void transpose64f(const float* p0, const float* p1, const float* p2, const float* p3,
                  ushort* q0, ushort* q1, ushort* q2, ushort* q3, int R, int C) {
  __shared__ float tile[64][68];
  const int z = blockIdx.z;
  const float* in = z == 0 ? p0 : z == 1 ? p1 : z == 2 ? p2 : p3;
  ushort* out = z == 0 ? q0 : z == 1 ? q1 : z == 2 ? q2 : q3;
  const int r0 = blockIdx.y * 64, c0 = blockIdx.x * 64;
  const int tid = threadIdx.x;
#pragma unroll
  for (int j = 0; j < 4; ++j) {
    int flat = j * 256 + tid;
    int row = flat >> 4, c4 = (flat & 15) * 4;
    float4 v = *(const float4*)(in + (size_t)(r0 + row) * C + c0 + c4);
    *(float4*)&tile[row][c4] = v;
  }
  __syncthreads();
#pragma unroll
  for (int j = 0; j < 4; ++j) {
    int flat = j * 256 + tid;
    int oc = flat >> 4, rq = (flat & 15) * 4;
    uint2 w;
    w.x = cvt_pk_bf16(tile[rq + 0][oc], tile[rq + 1][oc]);
    w.y = cvt_pk_bf16(tile[rq + 2][oc], tile[rq + 3][oc]);
    *(uint2*)(out + (size_t)(c0 + oc) * R + r0 + rq) = w;
  }
}

__global__ __launch_bounds__(256)
void transpose64h(const ushort* p0, const ushort* p1, const ushort* p2, const ushort* p3,
                  ushort* q0, ushort* q1, ushort* q2, ushort* q3, int R, int C) {
  __shared__ float tile[64][68];
  const int z = blockIdx.z;
  const ushort* in = z == 0 ? p0 : z == 1 ? p1 : z == 2 ? p2 : p3;
  ushort* out = z == 0 ? q0 : z == 1 ? q1 : z == 2 ? q2 : q3;
  const int r0 = blockIdx.y * 64, c0 = blockIdx.x * 64;
  const int tid = threadIdx.x;
#pragma unroll
  for (int j = 0; j < 2; ++j) {
    int flat = j * 256 + tid;
    int row = flat >> 3, c8 = (flat & 7) * 8;
    uint4 v = *(const uint4*)(in + (size_t)(r0 + row) * C + c0 + c8);
    float4 f0, f1;
    f0.x = bf2f((ushort)(v.x & 0xffff)); f0.y = bf2f((ushort)(v.x >> 16));
    f0.z = bf2f((ushort)(v.y & 0xffff)); f0.w = bf2f((ushort)(v.y >> 16));
    f1.x = bf2f((ushort)(v.z & 0xffff)); f1.y = bf2f((ushort)(v.z >> 16));
    f1.z = bf2f((ushort)(v.w & 0xffff)); f1.w = bf2f((ushort)(v.w >> 16));
    *(float4*)&tile[row][c8] = f0;
    *(float4*)&tile[row][c8 + 4] = f1;
  }
  __syncthreads();
#pragma unroll
  for (int j = 0; j < 4; ++j) {
    int flat = j * 256 + tid;
    int oc = flat >> 4, rq = (flat & 15) * 4;
    uint2 w;
    w.x = cvt_pk_bf16(tile[rq + 0][oc], tile[rq + 1][oc]);
    w.y = cvt_pk_bf16(tile[rq + 2][oc], tile[rq + 3][oc]);
    *(uint2*)(out + (size_t)(c0 + oc) * R + r0 + rq) = w;
  }
}

__global__ __launch_bounds__(256)
void pack_mask(const int* __restrict__ in, uint* __restrict__ out) {
  long t = (long)blockIdx.x * 256 + threadIdx.x;
  const int4* p = (const int4*)(in + t * 32);
  uint w = 0;
#pragma unroll
  for (int i = 0; i < 8; ++i) {
    int4 v = p[i];
    w |= (v.x > 0 ? 1u : 0u) << (i * 4 + 0);
    w |= (v.y > 0 ? 1u : 0u) << (i * 4 + 1);
    w |= (v.z > 0 ? 1u : 0u) << (i * 4 + 2);
    w |= (v.w > 0 ? 1u : 0u) << (i * 4 + 3);
  }
  out[t] = w;
}

// ---------- GEMM v3: 256x256 tile, counted-vmcnt + B-panel register cache ---
// Change vs r5: the wave's full B-panel (8 bf16x8 = 32 VGPR) is loaded ONCE
// per K-tile; A-frags per m-half (8 reads x 2). ds_read_b128 per K-tile per
// wave: 32 -> 24, flipping the kernel from LDS-bound (3072 cyc) to MFMA-bound
// (2483 cyc). VGPR ~217 < 256 budget at 2 waves/SIMD.

template<int OUT_BF16>
__global__ __launch_bounds__(512, 2)
void gemm256(const ushort* __restrict__ A, const ushort* __restrict__ Bt,
             void* __restrict__ C, int M, int N, int K, float scale) {
  __shared__ ushort lA[2][256 * 64];
  __shared__ ushort lB[2][256 * 64];
  const int tid = threadIdx.x;
  const int wid = tid >> 6, lane = tid & 63;
  const int lg = lane >> 4, li = lane & 15;
  const int wm = wid >> 2, wn = wid & 3;
  const int m0 = blockIdx.y * 256, n0 = blockIdx.x * 256;

  int offA[4], offB[4];
#pragma unroll
  for (int i = 0; i < 4; ++i) {
    int off = i * 8192 + tid * 16;
    int row = off >> 7;
    int col = (off & 127) ^ ((row & 7) << 4);
    offA[i] = (m0 + row) * (K * 2) + col;
    offB[i] = (n0 + row) * (K * 2) + col;
  }
  const char* Ab = (const char*)A;
  const char* Bb = (const char*)Bt;

#define STAGE256(bufi, ktb)                                                   \
  do {                                                                        \
    _Pragma("unroll") for (int i = 0; i < 4; ++i)                             \
      gload_lds16(Ab + (size_t)(offA[i] + (ktb)),                             \
                  (char*)lA[bufi] + i * 8192 + wid * 1024);                   \
    _Pragma("unroll") for (int i = 0; i < 4; ++i)                             \
      gload_lds16(Bb + (size_t)(offB[i] + (ktb)),                             \
                  (char*)lB[bufi] + i * 8192 + wid * 1024);                   \
  } while (0)

  f32x4 acc[8][4] = {};
  const int NT = K >> 6;

  STAGE256(0, 0);

  for (int t = 0; t < NT; ++t) {
    const int cur = t & 1;
    if (t > 0) __builtin_amdgcn_s_barrier();
    if (t + 1 < NT) {
      STAGE256(cur ^ 1, (t + 1) * 128);
      asm volatile("s_waitcnt vmcnt(8)" ::: "memory");
    } else {
      asm volatile("s_waitcnt vmcnt(0)" ::: "memory");
    }
    __builtin_amdgcn_s_barrier();
    __builtin_amdgcn_sched_barrier(0);

    const char* la = (const char*)lA[cur];
    const char* lb = (const char*)lB[cur];

    // whole wave B-panel once per K-tile: 8 x b128 (32 VGPR), reused 4x each
    bf16x8 bfr[4][2];
#pragma unroll
    for (int ni = 0; ni < 4; ++ni)
#pragma unroll
      for (int ks = 0; ks < 2; ++ks) {
        const int row = wn * 64 + ni * 16 + li;
        bfr[ni][ks] = *(const bf16x8*)(
            lb + row * 128 + ((ks * 64 + lg * 16) ^ ((li & 7) << 4)));
      }

    bf16x8 afr[4][2];
#pragma unroll
    for (int mh = 0; mh < 2; ++mh) {
      // A-frags for this m-half: 8 x b128, each reused 4x
#pragma unroll
      for (int mi = 0; mi < 4; ++mi)
#pragma unroll
        for (int ks = 0; ks < 2; ++ks) {
          const int row = wm * 128 + (mh * 4 + mi) * 16 + li;
          afr[mi][ks] = *(const bf16x8*)(
              la + row * 128 + ((ks * 64 + lg * 16) ^ ((li & 7) << 4)));
        }
      __builtin_amdgcn_s_setprio(1);
#pragma unroll
      for (int ks = 0; ks < 2; ++ks)
#pragma unroll
        for (int mi = 0; mi < 4; ++mi)
#pragma unroll
          for (int ni = 0; ni < 4; ++ni)
            acc[mh * 4 + mi][ni] = mfma32(
                afr[mi][ks], bfr[ni][ks], acc[mh * 4 + mi][ni], 0, 0, 0);
      __builtin_amdgcn_s_setprio(0);
    }
  }
#undef STAGE256

  const int r0 = m0 + wm * 128 + lg * 4;
  const int c0 = n0 + wn * 64 + li;
#pragma unroll
  for (int mi = 0; mi < 8; ++mi)
#pragma unroll
    for (int ni = 0; ni < 4; ++ni)
#pragma unroll
      for (int r = 0; r < 4; ++r) {
        size_t idx = (size_t)(r0 + mi * 16 + r) * N + (c0 + ni * 16);
        float v = acc[mi][ni][r] * scale;
        if (OUT_BF16) ((ushort*)C)[idx] = f2bf(v);
        else          ((float*)C)[idx]  = v;
      }
}

// ---------- flash attention v6.1 (round-9 verified: 199.5 us, unchanged) ----

__global__ __launch_bounds__(256, 2)
void flash_attn6(const ushort* __restrict__ Q, const ushort* __restrict__ K,
                 const ushort* __restrict__ VT, const uint* __restrict__ maskp,
                 ushort* __restrict__ X) {
  __shared__ ushort lK[2][64 * 128];    // [kv][hd], 256-B rows, swz (row&15)<<4
  __shared__ ushort lVT[2][128 * 64];   // [hd][kv], 128-B rows, swz (row&7)<<4
  __shared__ ushort lP[4][2][16 * 64];  // per-wave, per-group P^T [q][k]

  const int tid = threadIdx.x;
  const int wid = tid >> 6;
  const int lane = tid & 63;
  const int lg = lane >> 4, li = lane & 15;

  const int flat = blockIdx.x;
  const int xcd = flat & 7;
  const int j = flat >> 3;
  const int bh = xcd * 8 + (j >> 4);
  const int qt = j & 15;
  const int b = bh >> 4, h = bh & 15;
  const int q0 = qt * 128;
  const int qbase = q0 + wid * 32;

  bf16x8 bq[2][4];
#pragma unroll
  for (int g = 0; g < 2; ++g) {
    const ushort* qrow = Q + (size_t)(b * 2048 + qbase + g * 16 + li) * 2048 + h * 128;
#pragma unroll
    for (int kk = 0; kk < 4; ++kk)
      bq[g][kk] = *(const bf16x8*)(qrow + kk * 32 + lg * 8);
  }

  const uint* mqb[2] = {
      maskp + (size_t)(b * 2048 + qbase + li) * 64,
      maskp + (size_t)(b * 2048 + qbase + 16 + li) * 64};
  uint2 wcur[2] = {*(const uint2*)mqb[0], *(const uint2*)mqb[1]};

  f32x4 acc_o[2][8] = {};  // O^T[hd = f*16 + lg*4 + r][q = li]
  f32x4 acc_l[2] = {};     // every component = running row-sum l(q=li)
  float m[2] = {-3e38f, -3e38f};

  const short ob = (short)0x3F80;  // bf16 1.0
  const bf16x8 vone8 = {ob, ob, ob, ob, ob, ob, ob, ob};

  const char* gk[4];
  const char* gv[4];
#pragma unroll
  for (int i = 0; i < 4; ++i) {
    int fl = i * 4096 + tid * 16;
    int rowK = fl >> 8;
    int colK = (fl & 255) ^ ((rowK & 15) << 4);
    gk[i] = (const char*)K + ((size_t)(b * 2048 + rowK) * 2048 + h * 128) * 2 + colK;
    int rowV = fl >> 7;
    int colV = (fl & 127) ^ ((rowV & 7) << 4);
    gv[i] = (const char*)VT + ((size_t)((b * 16 + h) * 128 + rowV) * 2048) * 2 + colV;
  }

#define FSTAGE(bufi)                                                          \
  do {                                                                        \
    _Pragma("unroll") for (int i = 0; i < 4; ++i)                             \
      gload_lds16(gk[i], (char*)lK[bufi] + i * 4096 + wid * 1024);            \
    _Pragma("unroll") for (int i = 0; i < 4; ++i)                             \
      gload_lds16(gv[i], (char*)lVT[bufi] + i * 4096 + wid * 1024);           \
    _Pragma("unroll") for (int i = 0; i < 4; ++i) {                           \
      gk[i] += 262144; gv[i] += 128;                                          \
    }                                                                         \
  } while (0)

  FSTAGE(0);

  ushort* lp0 = lP[wid][0];
  ushort* lp1 = lP[wid][1];

#pragma unroll 2
  for (int it = 0; it < 32; ++it) {
    const int cur = it & 1;
    if (it > 0) __builtin_amdgcn_s_barrier();
    uint2 wn[2];
    if (it < 31) {
      FSTAGE(cur ^ 1);
      wn[0] = *(const uint2*)(mqb[0] + (it + 1) * 2);
      wn[1] = *(const uint2*)(mqb[1] + (it + 1) * 2);
      asm volatile("s_waitcnt vmcnt(10)" ::: "memory");
    } else {
      asm volatile("s_waitcnt vmcnt(0)" ::: "memory");
    }
    __builtin_amdgcn_s_barrier();
    __builtin_amdgcn_sched_barrier(0);

    const char* lk = (const char*)lK[cur];
    const char* lv = (const char*)lVT[cur];

    // QK^T swapped (16x16x32): accs[g][n] = S[k=n*16+lg*4+r][q=li]
    f32x4 accs[2][4] = {};
    __builtin_amdgcn_s_setprio(1);
#pragma unroll
    for (int kk = 0; kk < 4; ++kk)
#pragma unroll
      for (int n = 0; n < 4; ++n) {
        bf16x8 ak = *(const bf16x8*)(lk + (n * 16 + li) * 256 +
                                     ((kk * 64 + lg * 16) ^ (li << 4)));
        accs[0][n] = mfma32(ak, bq[0][kk], accs[0][n], 0, 0, 0);
        accs[1][n] = mfma32(ak, bq[1][kk], accs[1][n], 0, 0, 0);
      }
    __builtin_amdgcn_s_setprio(0);

    // softmax per group (exp2 domain); P -> per-wave LDS via cvt_pk
#pragma unroll
    for (int g = 0; g < 2; ++g) {
      float sv[16];
#pragma unroll
      for (int n = 0; n < 4; ++n) {
        uint w = (n < 2) ? wcur[g].x : wcur[g].y;
#pragma unroll
        for (int r = 0; r < 4; ++r) {
          int bit = (n & 1) * 16 + lg * 4 + r;
          sv[n * 4 + r] = ((w >> bit) & 1u) ? accs[g][n][r] : -1e10f;
        }
      }
      // max3-fusable tree (T17)
      float t0 = fmaxf(fmaxf(sv[0], sv[1]), sv[2]);
      float t1 = fmaxf(fmaxf(sv[3], sv[4]), sv[5]);
      float t2 = fmaxf(fmaxf(sv[6], sv[7]), sv[8]);
      float t3 = fmaxf(fmaxf(sv[9], sv[10]), sv[11]);
      float t4 = fmaxf(fmaxf(sv[12], sv[13]), sv[14]);
      float pmax = fmaxf(fmaxf(fmaxf(t0, t1), t2),
                         fmaxf(fmaxf(t3, t4), sv[15]));
      pmax = fmaxf(pmax, __shfl_xor(pmax, 16, 64));
      pmax = fmaxf(pmax, __shfl_xor(pmax, 32, 64));

      // defer-max: 11.5 ~= 8 * log2(e)
      if (!__all(pmax - m[g] <= 11.5f)) {
        float mnew = fmaxf(m[g], pmax);
        float alpha = fexp2(m[g] - mnew);
#pragma unroll
        for (int r = 0; r < 4; ++r) acc_l[g][r] *= alpha;
#pragma unroll
        for (int f = 0; f < 8; ++f)
#pragma unroll
          for (int r = 0; r < 4; ++r) acc_o[g][f][r] *= alpha;
        m[g] = mnew;
      }

      uint pk[8];
#pragma unroll
      for (int i = 0; i < 8; ++i) {
        float p0 = fexp2(sv[2 * i] - m[g]);      // bounded by 2^11.5
        float p1 = fexp2(sv[2 * i + 1] - m[g]);
        pk[i] = cvt_pk_bf16(p0, p1);
      }

      ushort* lpg = g ? lp1 : lp0;
#pragma unroll
      for (int n = 0; n < 4; ++n) {
        uint2 pw; pw.x = pk[2 * n]; pw.y = pk[2 * n + 1];
        *(uint2*)((char*)lpg + li * 128 + ((n * 32 + lg * 8) ^ ((li & 7) << 4))) = pw;
      }
    }
    // in-order per-wave DS pipe: ds_write -> ds_read RAW safe without barrier

    // PV fused over both groups (16x16x32): av read ONCE per (kc,f);
    // l accumulated via ones-MFMA on the same bp fragments.
    __builtin_amdgcn_s_setprio(1);
#pragma unroll
    for (int kc = 0; kc < 2; ++kc) {
      bf16x8 bp0 = *(const bf16x8*)((const char*)lp0 + li * 128 +
                                    ((kc * 64 + lg * 16) ^ ((li & 7) << 4)));
      bf16x8 bp1 = *(const bf16x8*)((const char*)lp1 + li * 128 +
                                    ((kc * 64 + lg * 16) ^ ((li & 7) << 4)));
      acc_l[0] = mfma32(vone8, bp0, acc_l[0], 0, 0, 0);
      acc_l[1] = mfma32(vone8, bp1, acc_l[1], 0, 0, 0);
#pragma unroll
      for (int f = 0; f < 8; ++f) {
        bf16x8 av = *(const bf16x8*)(lv + (f * 16 + li) * 128 +
                                     ((kc * 64 + lg * 16) ^ ((li & 7) << 4)));
        acc_o[0][f] = mfma32(av, bp0, acc_o[0][f], 0, 0, 0);
        acc_o[1][f] = mfma32(av, bp1, acc_o[1][f], 0, 0, 0);
      }
    }
    __builtin_amdgcn_s_setprio(0);

    if (it < 31) { wcur[0] = wn[0]; wcur[1] = wn[1]; }
  }
#undef FSTAGE

  // epilogue: O[q][hd] = acc_o / l  (acc_l rows all equal l(q=li))
#pragma unroll
  for (int g = 0; g < 2; ++g) {
    const float inv_l = 1.0f / acc_l[g][0];
    ushort* xrow = X + (size_t)(b * 2048 + qbase + g * 16 + li) * 2048 + h * 128;
#pragma unroll
    for (int f = 0; f < 8; ++f) {
      union { ushort u[4]; uint2 v; } o;
#pragma unroll
      for (int r = 0; r < 4; ++r) o.u[r] = f2bf(acc_o[g][f][r] * inv_l);
      *(uint2*)(xrow + f * 16 + lg * 4) = o.v;
    }
  }
}

// ---------- launch ----------

extern "C" void kernel_launch(void* const* d_in, const int* in_sizes, int n_in,
                              void* d_out, int out_size, void* d_ws, size_t ws_size,
                              hipStream_t stream) {
  const float* inputs_q  = (const float*)d_in[0];
  const float* inputs_kv = (const float*)d_in[1];
  const int*   mask      = (const int*)d_in[2];
  const float* Wq        = (const float*)d_in[3];
  const float* Wk        = (const float*)d_in[4];
  const float* Wv        = (const float*)d_in[5];
  const float* Wo        = (const float*)d_in[6];
  float* out = (float*)d_out;
  char* ws = (char*)d_ws;

  uint*   maskp = (uint*)(ws + 0);                 //   2,097,152
  ushort* xq    = (ushort*)(ws + 2097152);         //  33,554,432 (reused as VT)
  ushort* xkv   = (ushort*)(ws + 35651584);        //  33,554,432 (reused as X)
  ushort* WqT   = (ushort*)(ws + 69206016);        //   8,388,608
  ushort* WkT   = (ushort*)(ws + 77594624);
  ushort* WvT   = (ushort*)(ws + 85983232);
  ushort* WoT   = (ushort*)(ws + 94371840);
  ushort* Qb    = (ushort*)(ws + 102760448);       //  33,554,432
  ushort* Kb    = (ushort*)(ws + 136314880);
  ushort* Vb    = (ushort*)(ws + 169869312);
  ushort* VTb   = xq;   // V^T, written after xq dead
  ushort* Xb    = xkv;  // attention output, written after xkv dead

  const long NE = 8192L * 2048;
  conv_bf16_2<<<16384, 256, 0, stream>>>(inputs_q, inputs_kv, xq, xkv, NE);

  transpose64f<<<dim3(32, 32, 4), 256, 0, stream>>>(
      Wq, Wk, Wv, Wo, WqT, WkT, WvT, WoT, 2048, 2048);

  pack_mask<<<2048, 256, 0, stream>>>(mask, maskp);

  // 1/sqrt(128) * log2(e): softmax runs in exp2 domain
  const float qscale = 0.12751744504593677f;
  gemm256<1><<<dim3(8, 32), 512, 0, stream>>>(xq,  WqT, Qb, 8192, 2048, 2048, qscale);
  gemm256<1><<<dim3(8, 32), 512, 0, stream>>>(xkv, WkT, Kb, 8192, 2048, 2048, 1.0f);
  gemm256<1><<<dim3(8, 32), 512, 0, stream>>>(xkv, WvT, Vb, 8192, 2048, 2048, 1.0f);

  const long BS = 2048L * 2048;
  transpose64h<<<dim3(32, 32, 4), 256, 0, stream>>>(
      Vb, Vb + BS, Vb + 2 * BS, Vb + 3 * BS,
      VTb, VTb + BS, VTb + 2 * BS, VTb + 3 * BS, 2048, 2048);

  flash_attn6<<<1024, 256, 0, stream>>>(Qb, Kb, VTb, maskp, Xb);

  gemm256<0><<<dim3(8, 32), 512, 0, stream>>>(Xb, WoT, out, 8192, 2048, 2048, 1.0f);
}

// Round 15
// 544.904 us; speedup vs baseline: 1.8489x; 1.0448x over previous
//
#include <hip/hip_runtime.h>

typedef __attribute__((ext_vector_type(4))) float f32x4;
typedef __attribute__((ext_vector_type(8))) short bf16x8;
typedef unsigned int uint;
typedef unsigned short ushort;

#define mfma32 __builtin_amdgcn_mfma_f32_16x16x32_bf16

// ---------- helpers ----------

__device__ __forceinline__ ushort f2bf(float f) {
  union { float f; uint u; } v; v.f = f;
  uint u = v.u;
  uint r = (u + 0x7FFFu + ((u >> 16) & 1u)) >> 16;  // RNE
  return (ushort)r;
}

// packed f32x2 -> bf16x2 (RNE), 1 instruction
__device__ __forceinline__ uint cvt_pk_bf16(float lo, float hi) {
  uint r;
  asm("v_cvt_pk_bf16_f32 %0, %1, %2" : "=v"(r) : "v"(lo), "v"(hi));
  return r;
}

// exp2 (v_exp_f32 IS base-2 exp)
__device__ __forceinline__ float fexp2(float x) {
  float r;
  asm("v_exp_f32 %0, %1" : "=v"(r) : "v"(x));
  return r;
}

__device__ __forceinline__ void gload_lds16(const void* g, void* l) {
  __builtin_amdgcn_global_load_lds(
      (const __attribute__((address_space(1))) void*)g,
      (__attribute__((address_space(3))) void*)l, 16, 0, 0);
}

// ---------- fused pre-pass: conv(2) + weight-transpose(4) + mask-pack ------
// One dispatch, 22528 blocks, block-uniform branch:
//   [0, 16384)      : f32->bf16 convert of inputs_q / inputs_kv
//   [16384, 20480)  : 64x64 weight transpose->bf16 (z = matrix)
//   [20480, 22528)  : mask bit-pack

__global__ __launch_bounds__(256)
void prepass(const float* __restrict__ iq, const float* __restrict__ ikv,
             ushort* __restrict__ xq, ushort* __restrict__ xkv,
             const float* __restrict__ Wq, const float* __restrict__ Wk,
             const float* __restrict__ Wv, const float* __restrict__ Wo,
             ushort* __restrict__ WqT, ushort* __restrict__ WkT,
             ushort* __restrict__ WvT, ushort* __restrict__ WoT,
             const int* __restrict__ mask, uint* __restrict__ maskp) {
  __shared__ float tile[64][68];
  const int bid = blockIdx.x;
  const int tid = threadIdx.x;

  if (bid < 16384) {
    // ---- f32 -> bf16 convert, 8 elems/thread ----
    const bool second = bid >= 8192;
    const float* in = second ? ikv : iq;
    ushort* out = second ? xkv : xq;
    long i = ((long)(bid & 8191) * 256 + tid) * 8;
    float4 x = *(const float4*)(in + i);
    float4 y = *(const float4*)(in + i + 4);
    union { uint u[4]; uint4 v; } o;
    o.u[0] = cvt_pk_bf16(x.x, x.y);
    o.u[1] = cvt_pk_bf16(x.z, x.w);
    o.u[2] = cvt_pk_bf16(y.x, y.y);
    o.u[3] = cvt_pk_bf16(y.z, y.w);
    *(uint4*)(out + i) = o.v;
  } else if (bid < 20480) {
    // ---- 64x64 f32 transpose -> bf16 (weights, 2048x2048) ----
    const int t = bid - 16384;
    const int z = t >> 10;
    const int by = (t >> 5) & 31, bx = t & 31;
    const float* in = z == 0 ? Wq : z == 1 ? Wk : z == 2 ? Wv : Wo;
    ushort* out = z == 0 ? WqT : z == 1 ? WkT : z == 2 ? WvT : WoT;
    const int r0 = by * 64, c0 = bx * 64;
#pragma unroll
    for (int j = 0; j < 4; ++j) {
      int flat = j * 256 + tid;
      int row = flat >> 4, c4 = (flat & 15) * 4;
      float4 v = *(const float4*)(in + (size_t)(r0 + row) * 2048 + c0 + c4);
      *(float4*)&tile[row][c4] = v;
    }
    __syncthreads();
#pragma unroll
    for (int j = 0; j < 4; ++j) {
      int flat = j * 256 + tid;
      int oc = flat >> 4, rq = (flat & 15) * 4;
      uint2 w;
      w.x = cvt_pk_bf16(tile[rq + 0][oc], tile[rq + 1][oc]);
      w.y = cvt_pk_bf16(tile[rq + 2][oc], tile[rq + 3][oc]);
      *(uint2*)(out + (size_t)(c0 + oc) * 2048 + r0 + rq) = w;
    }
  } else {
    // ---- mask int32 -> bit-packed u32 ----
    long t = (long)(bid - 20480) * 256 + tid;
    const int4* p = (const int4*)(mask + t * 32);
    uint w = 0;
#pragma unroll
    for (int i = 0; i < 8; ++i) {
      int4 v = p[i];
      w |= (v.x > 0 ? 1u : 0u) << (i * 4 + 0);
      w |= (v.y > 0 ? 1u : 0u) << (i * 4 + 1);
      w |= (v.z > 0 ? 1u : 0u) << (i * 4 + 2);
      w |= (v.w > 0 ? 1u : 0u) << (i * 4 + 3);
    }
    maskp[t] = w;
  }
}

// ---------- GEMM: 256x256 tile, counted-vmcnt + B-panel register cache -----
// OUT_MODE: 0 = f32 row-major, 1 = bf16 row-major,
//           2 = bf16 transposed-per-batch (writes V^T layout directly:
//               VT[(b*2048 + col)*2048 + s]; acc's 4 r-values are contiguous
//               in s -> 8B stores). NOTE: col = c0 + ni*16 ALREADY contains
//               li (c0 = n0 + wn*64 + li) — do not add li again (r14 bug).

template<int OUT_MODE>
__global__ __launch_bounds__(512, 2)
void gemm256(const ushort* __restrict__ A, const ushort* __restrict__ Bt,
             void* __restrict__ C, int M, int N, int K, float scale) {
  __shared__ ushort lA[2][256 * 64];
  __shared__ ushort lB[2][256 * 64];
  const int tid = threadIdx.x;
  const int wid = tid >> 6, lane = tid & 63;
  const int lg = lane >> 4, li = lane & 15;
  const int wm = wid >> 2, wn = wid & 3;
  const int m0 = blockIdx.y * 256, n0 = blockIdx.x * 256;

  int offA[4], offB[4];
#pragma unroll
  for (int i = 0; i < 4; ++i) {
    int off = i * 8192 + tid * 16;
    int row = off >> 7;
    int col = (off & 127) ^ ((row & 7) << 4);
    offA[i] = (m0 + row) * (K * 2) + col;
    offB[i] = (n0 + row) * (K * 2) + col;
  }
  const char* Ab = (const char*)A;
  const char* Bb = (const char*)Bt;

#define STAGE256(bufi, ktb)                                                   \
  do {                                                                        \
    _Pragma("unroll") for (int i = 0; i < 4; ++i)                             \
      gload_lds16(Ab + (size_t)(offA[i] + (ktb)),                             \
                  (char*)lA[bufi] + i * 8192 + wid * 1024);                   \
    _Pragma("unroll") for (int i = 0; i < 4; ++i)                             \
      gload_lds16(Bb + (size_t)(offB[i] + (ktb)),                             \
                  (char*)lB[bufi] + i * 8192 + wid * 1024);                   \
  } while (0)

  f32x4 acc[8][4] = {};
  const int NT = K >> 6;

  STAGE256(0, 0);

  for (int t = 0; t < NT; ++t) {
    const int cur = t & 1;
    if (t > 0) __builtin_amdgcn_s_barrier();
    if (t + 1 < NT) {
      STAGE256(cur ^ 1, (t + 1) * 128);
      asm volatile("s_waitcnt vmcnt(8)" ::: "memory");
    } else {
      asm volatile("s_waitcnt vmcnt(0)" ::: "memory");
    }
    __builtin_amdgcn_s_barrier();
    __builtin_amdgcn_sched_barrier(0);

    const char* la = (const char*)lA[cur];
    const char* lb = (const char*)lB[cur];

    // whole wave B-panel once per K-tile: 8 x b128 (32 VGPR), reused 4x each
    bf16x8 bfr[4][2];
#pragma unroll
    for (int ni = 0; ni < 4; ++ni)
#pragma unroll
      for (int ks = 0; ks < 2; ++ks) {
        const int row = wn * 64 + ni * 16 + li;
        bfr[ni][ks] = *(const bf16x8*)(
            lb + row * 128 + ((ks * 64 + lg * 16) ^ ((li & 7) << 4)));
      }

    bf16x8 afr[4][2];
#pragma unroll
    for (int mh = 0; mh < 2; ++mh) {
#pragma unroll
      for (int mi = 0; mi < 4; ++mi)
#pragma unroll
        for (int ks = 0; ks < 2; ++ks) {
          const int row = wm * 128 + (mh * 4 + mi) * 16 + li;
          afr[mi][ks] = *(const bf16x8*)(
              la + row * 128 + ((ks * 64 + lg * 16) ^ ((li & 7) << 4)));
        }
      __builtin_amdgcn_s_setprio(1);
#pragma unroll
      for (int ks = 0; ks < 2; ++ks)
#pragma unroll
        for (int mi = 0; mi < 4; ++mi)
#pragma unroll
          for (int ni = 0; ni < 4; ++ni)
            acc[mh * 4 + mi][ni] = mfma32(
                afr[mi][ks], bfr[ni][ks], acc[mh * 4 + mi][ni], 0, 0, 0);
      __builtin_amdgcn_s_setprio(0);
    }
  }
#undef STAGE256

  const int r0 = m0 + wm * 128 + lg * 4;
  const int c0 = n0 + wn * 64 + li;
  if constexpr (OUT_MODE == 2) {
    // transposed-per-batch epilogue (V^T): 8B stores, r contiguous in s
    const int b_ = r0 >> 11;
    const int s0 = r0 & 2047;
    ushort* VT = (ushort*)C;
#pragma unroll
    for (int mi = 0; mi < 8; ++mi)
#pragma unroll
      for (int ni = 0; ni < 4; ++ni) {
        union { ushort u[4]; uint2 v; } o;
#pragma unroll
        for (int r = 0; r < 4; ++r) o.u[r] = f2bf(acc[mi][ni][r] * scale);
        *(uint2*)(VT + ((size_t)(b_ * 2048 + c0 + ni * 16)) * 2048 +
                  s0 + mi * 16) = o.v;
      }
  } else {
#pragma unroll
    for (int mi = 0; mi < 8; ++mi)
#pragma unroll
      for (int ni = 0; ni < 4; ++ni)
#pragma unroll
        for (int r = 0; r < 4; ++r) {
          size_t idx = (size_t)(r0 + mi * 16 + r) * N + (c0 + ni * 16);
          float v = acc[mi][ni][r] * scale;
          if (OUT_MODE == 1) ((ushort*)C)[idx] = f2bf(v);
          else               ((float*)C)[idx]  = v;
        }
  }
}

// ---------- flash attention v6.2 (single barrier per KV iteration) ----------
// vmcnt(0) retires tile-t loads (issued a full iteration ago, nothing newer
// outstanding) -> barrier (ends prev compute AND publishes tile t) ->
// STAGE(t+1) -> compute(t). One 4-wave rendezvous per iter instead of two.

__global__ __launch_bounds__(256, 2)
void flash_attn6(const ushort* __restrict__ Q, const ushort* __restrict__ K,
                 const ushort* __restrict__ VT, const uint* __restrict__ maskp,
                 ushort* __restrict__ X) {
  __shared__ ushort lK[2][64 * 128];    // [kv][hd], 256-B rows, swz (row&15)<<4
  __shared__ ushort lVT[2][128 * 64];   // [hd][kv], 128-B rows, swz (row&7)<<4
  __shared__ ushort lP[4][2][16 * 64];  // per-wave, per-group P^T [q][k]

  const int tid = threadIdx.x;
  const int wid = tid >> 6;
  const int lane = tid & 63;
  const int lg = lane >> 4, li = lane & 15;

  const int flat = blockIdx.x;
  const int xcd = flat & 7;
  const int j = flat >> 3;
  const int bh = xcd * 8 + (j >> 4);
  const int qt = j & 15;
  const int b = bh >> 4, h = bh & 15;
  const int q0 = qt * 128;
  const int qbase = q0 + wid * 32;

  bf16x8 bq[2][4];
#pragma unroll
  for (int g = 0; g < 2; ++g) {
    const ushort* qrow = Q + (size_t)(b * 2048 + qbase + g * 16 + li) * 2048 + h * 128;
#pragma unroll
    for (int kk = 0; kk < 4; ++kk)
      bq[g][kk] = *(const bf16x8*)(qrow + kk * 32 + lg * 8);
  }

  const uint* mqb[2] = {
      maskp + (size_t)(b * 2048 + qbase + li) * 64,
      maskp + (size_t)(b * 2048 + qbase + 16 + li) * 64};
  uint2 wcur[2] = {*(const uint2*)mqb[0], *(const uint2*)mqb[1]};

  f32x4 acc_o[2][8] = {};  // O^T[hd = f*16 + lg*4 + r][q = li]
  f32x4 acc_l[2] = {};     // every component = running row-sum l(q=li)
  float m[2] = {-3e38f, -3e38f};

  const short ob = (short)0x3F80;  // bf16 1.0
  const bf16x8 vone8 = {ob, ob, ob, ob, ob, ob, ob, ob};

  const char* gk[4];
  const char* gv[4];
#pragma unroll
  for (int i = 0; i < 4; ++i) {
    int fl = i * 4096 + tid * 16;
    int rowK = fl >> 8;
    int colK = (fl & 255) ^ ((rowK & 15) << 4);
    gk[i] = (const char*)K + ((size_t)(b * 2048 + rowK) * 2048 + h * 128) * 2 + colK;
    int rowV = fl >> 7;
    int colV = (fl & 127) ^ ((rowV & 7) << 4);
    gv[i] = (const char*)VT + ((size_t)((b * 16 + h) * 128 + rowV) * 2048) * 2 + colV;
  }

#define FSTAGE(bufi)                                                          \
  do {                                                                        \
    _Pragma("unroll") for (int i = 0; i < 4; ++i)                             \
      gload_lds16(gk[i], (char*)lK[bufi] + i * 4096 + wid * 1024);            \
    _Pragma("unroll") for (int i = 0; i < 4; ++i)                             \
      gload_lds16(gv[i], (char*)lVT[bufi] + i * 4096 + wid * 1024);           \
    _Pragma("unroll") for (int i = 0; i < 4; ++i) {                           \
      gk[i] += 262144; gv[i] += 128;                                          \
    }                                                                         \
  } while (0)

  FSTAGE(0);

  ushort* lp0 = lP[wid][0];
  ushort* lp1 = lP[wid][1];

#pragma unroll 2
  for (int it = 0; it < 32; ++it) {
    const int cur = it & 1;
    // retire tile-it loads (issued one full iteration ago; nothing newer
    // outstanding), then one barrier: ends the previous compute (WAR for
    // buf cur^1) AND publishes tile it to all waves.
    asm volatile("s_waitcnt vmcnt(0)" ::: "memory");
    __builtin_amdgcn_s_barrier();
    __builtin_amdgcn_sched_barrier(0);

    uint2 wn[2];
    if (it < 31) {
      FSTAGE(cur ^ 1);  // tile it+1 -> freed buffer; lands during compute(it)
      wn[0] = *(const uint2*)(mqb[0] + (it + 1) * 2);
      wn[1] = *(const uint2*)(mqb[1] + (it + 1) * 2);
    }

    const char* lk = (const char*)lK[cur];
    const char* lv = (const char*)lVT[cur];

    // QK^T swapped (16x16x32): accs[g][n] = S[k=n*16+lg*4+r][q=li]
    f32x4 accs[2][4] = {};
    __builtin_amdgcn_s_setprio(1);
#pragma unroll
    for (int kk = 0; kk < 4; ++kk)
#pragma unroll
      for (int n = 0; n < 4; ++n) {
        bf16x8 ak = *(const bf16x8*)(lk + (n * 16 + li) * 256 +
                                     ((kk * 64 + lg * 16) ^ (li << 4)));
        accs[0][n] = mfma32(ak, bq[0][kk], accs[0][n], 0, 0, 0);
        accs[1][n] = mfma32(ak, bq[1][kk], accs[1][n], 0, 0, 0);
      }
    __builtin_amdgcn_s_setprio(0);

    // softmax per group (exp2 domain); P -> per-wave LDS via cvt_pk
#pragma unroll
    for (int g = 0; g < 2; ++g) {
      float sv[16];
#pragma unroll
      for (int n = 0; n < 4; ++n) {
        uint w = (n < 2) ? wcur[g].x : wcur[g].y;
#pragma unroll
        for (int r = 0; r < 4; ++r) {
          int bit = (n & 1) * 16 + lg * 4 + r;
          sv[n * 4 + r] = ((w >> bit) & 1u) ? accs[g][n][r] : -1e10f;
        }
      }
      // max3-fusable tree (T17)
      float t0 = fmaxf(fmaxf(sv[0], sv[1]), sv[2]);
      float t1 = fmaxf(fmaxf(sv[3], sv[4]), sv[5]);
      float t2 = fmaxf(fmaxf(sv[6], sv[7]), sv[8]);
      float t3 = fmaxf(fmaxf(sv[9], sv[10]), sv[11]);
      float t4 = fmaxf(fmaxf(sv[12], sv[13]), sv[14]);
      float pmax = fmaxf(fmaxf(fmaxf(t0, t1), t2),
                         fmaxf(fmaxf(t3, t4), sv[15]));
      pmax = fmaxf(pmax, __shfl_xor(pmax, 16, 64));
      pmax = fmaxf(pmax, __shfl_xor(pmax, 32, 64));

      // defer-max: 11.5 ~= 8 * log2(e)
      if (!__all(pmax - m[g] <= 11.5f)) {
        float mnew = fmaxf(m[g], pmax);
        float alpha = fexp2(m[g] - mnew);
#pragma unroll
        for (int r = 0; r < 4; ++r) acc_l[g][r] *= alpha;
#pragma unroll
        for (int f = 0; f < 8; ++f)
#pragma unroll
          for (int r = 0; r < 4; ++r) acc_o[g][f][r] *= alpha;
        m[g] = mnew;
      }

      uint pk[8];
#pragma unroll
      for (int i = 0; i < 8; ++i) {
        float p0 = fexp2(sv[2 * i] - m[g]);      // bounded by 2^11.5
        float p1 = fexp2(sv[2 * i + 1] - m[g]);
        pk[i] = cvt_pk_bf16(p0, p1);
      }

      ushort* lpg = g ? lp1 : lp0;
#pragma unroll
      for (int n = 0; n < 4; ++n) {
        uint2 pw; pw.x = pk[2 * n]; pw.y = pk[2 * n + 1];
        *(uint2*)((char*)lpg + li * 128 + ((n * 32 + lg * 8) ^ ((li & 7) << 4))) = pw;
      }
    }
    // in-order per-wave DS pipe: ds_write -> ds_read RAW safe without barrier

    // PV fused over both groups (16x16x32): av read ONCE per (kc,f);
    // l accumulated via ones-MFMA on the same bp fragments.
    __builtin_amdgcn_s_setprio(1);
#pragma unroll
    for (int kc = 0; kc < 2; ++kc) {
      bf16x8 bp0 = *(const bf16x8*)((const char*)lp0 + li * 128 +
                                    ((kc * 64 + lg * 16) ^ ((li & 7) << 4)));
      bf16x8 bp1 = *(const bf16x8*)((const char*)lp1 + li * 128 +
                                    ((kc * 64 + lg * 16) ^ ((li & 7) << 4)));
      acc_l[0] = mfma32(vone8, bp0, acc_l[0], 0, 0, 0);
      acc_l[1] = mfma32(vone8, bp1, acc_l[1], 0, 0, 0);
#pragma unroll
      for (int f = 0; f < 8; ++f) {
        bf16x8 av = *(const bf16x8*)(lv + (f * 16 + li) * 128 +
                                     ((kc * 64 + lg * 16) ^ ((li & 7) << 4)));
        acc_o[0][f] = mfma32(av, bp0, acc_o[0][f], 0, 0, 0);
        acc_o[1][f] = mfma32(av, bp1, acc_o[1][f], 0, 0, 0);
      }
    }
    __builtin_amdgcn_s_setprio(0);

    if (it < 31) { wcur[0] = wn[0]; wcur[1] = wn[1]; }
  }
#undef FSTAGE

  // epilogue: O[q][hd] = acc_o / l  (acc_l rows all equal l(q=li))
#pragma unroll
  for (int g = 0; g < 2; ++g) {
    const float inv_l = 1.0f / acc_l[g][0];
    ushort* xrow = X + (size_t)(b * 2048 + qbase + g * 16 + li) * 2048 + h * 128;
#pragma unroll
    for (int f = 0; f < 8; ++f) {
      union { ushort u[4]; uint2 v; } o;
#pragma unroll
      for (int r = 0; r < 4; ++r) o.u[r] = f2bf(acc_o[g][f][r] * inv_l);
      *(uint2*)(xrow + f * 16 + lg * 4) = o.v;
    }
  }
}

// ---------- launch ----------

extern "C" void kernel_launch(void* const* d_in, const int* in_sizes, int n_in,
                              void* d_out, int out_size, void* d_ws, size_t ws_size,
                              hipStream_t stream) {
  const float* inputs_q  = (const float*)d_in[0];
  const float* inputs_kv = (const float*)d_in[1];
  const int*   mask      = (const int*)d_in[2];
  const float* Wq        = (const float*)d_in[3];
  const float* Wk        = (const float*)d_in[4];
  const float* Wv        = (const float*)d_in[5];
  const float* Wo        = (const float*)d_in[6];
  float* out = (float*)d_out;
  char* ws = (char*)d_ws;

  uint*   maskp = (uint*)(ws + 0);                 //   2,097,152
  ushort* xq    = (ushort*)(ws + 2097152);         //  33,554,432 (reused as VT)
  ushort* xkv   = (ushort*)(ws + 35651584);        //  33,554,432 (reused as X)
  ushort* WqT   = (ushort*)(ws + 69206016);        //   8,388,608
  ushort* WkT   = (ushort*)(ws + 77594624);
  ushort* WvT   = (ushort*)(ws + 85983232);
  ushort* WoT   = (ushort*)(ws + 94371840);
  ushort* Qb    = (ushort*)(ws + 102760448);       //  33,554,432
  ushort* Kb    = (ushort*)(ws + 136314880);
  ushort* VTb   = xq;   // V^T written DIRECTLY by the V GEMM (xq dead by then)
  ushort* Xb    = xkv;  // attention output, written after xkv dead

  // one fused pre-pass dispatch: conv(16384) + transpose(4096) + pack(2048)
  prepass<<<22528, 256, 0, stream>>>(inputs_q, inputs_kv, xq, xkv,
                                     Wq, Wk, Wv, Wo, WqT, WkT, WvT, WoT,
                                     mask, maskp);

  // 1/sqrt(128) * log2(e): softmax runs in exp2 domain
  const float qscale = 0.12751744504593677f;
  gemm256<1><<<dim3(8, 32), 512, 0, stream>>>(xq,  WqT, Qb, 8192, 2048, 2048, qscale);
  gemm256<1><<<dim3(8, 32), 512, 0, stream>>>(xkv, WkT, Kb, 8192, 2048, 2048, 1.0f);
  // V GEMM writes V^T layout directly (OUT_MODE=2); transpose kernel gone
  gemm256<2><<<dim3(8, 32), 512, 0, stream>>>(xkv, WvT, VTb, 8192, 2048, 2048, 1.0f);

  flash_attn6<<<1024, 256, 0, stream>>>(Qb, Kb, VTb, maskp, Xb);

  gemm256<0><<<dim3(8, 32), 512, 0, stream>>>(Xb, WoT, out, 8192, 2048, 2048, 1.0f);
}